// Round 6
// baseline (6845.116 us; speedup 1.0000x reference)
//
#include <hip/hip_runtime.h>
#include <stdint.h>
#include <math.h>

// ============================================================================
// MCFNet on MI355X (gfx950).  INPUTS FLOAT32; OUTPUT FLOAT32.
// Numerics: all tensors stored f32.  Every matmul runs on MFMA bf16 with
// on-the-fly 3-plane splits (x = h + m + l, rep error ~2^-27) and 6 passes
// (hh, hm, mh, hl, lh, mm; dropped terms <= 2^-27).  Weights pre-split into
// 3 transposed bf16 planes.  RoPE theta = f32-rounded double pow (matches
// numpy's correctly-rounded powf).  Softmax/gates mirror numpy op order.
// Residual error vs np f32 reference ~ accumulation-order noise only.
// Memory: batch-local network -> stream whole-batch chunks through 6 f32
// planes; Mc chosen at runtime to fit ws_size (constant across calls).
// ============================================================================

typedef unsigned short USH;
typedef __attribute__((ext_vector_type(8))) short short8;
typedef __attribute__((ext_vector_type(4))) float floatx4;

#define MFMA16(a, b, c) __builtin_amdgcn_mfma_f32_16x16x32_bf16((a), (b), (c), 0, 0, 0)

static constexpr int NB = 32;          // batch
static constexpr int SS = 512;         // seq len
static constexpr int DD = 768;         // model dim
static constexpr int MM = NB * SS;     // 16384 rows

__device__ __forceinline__ float bf2f(USH h) {
    return __uint_as_float(((unsigned)h) << 16);
}
__device__ __forceinline__ USH f2bf(float x) {          // round-to-nearest-even
    unsigned u = __float_as_uint(x);
    return (USH)((u + 0x7fffu + ((u >> 16) & 1u)) >> 16);
}
// 3-plane split: x = h + m + l + err, |err| <= 2^-27 |x| (residuals exact).
__device__ __forceinline__ void split3(float x, USH &h, USH &m, USH &l) {
    h = f2bf(x);
    const float r1 = x - bf2f(h);
    m = f2bf(r1);
    const float r2 = r1 - bf2f(m);
    l = f2bf(r2);
}
__device__ __forceinline__ void split3x8(const float* v, short8 &H, short8 &M, short8 &L) {
#pragma unroll
    for (int j = 0; j < 8; ++j) {
        USH h, m, l;
        split3(v[j], h, m, l);
        H[j] = (short)h; M[j] = (short)m; L[j] = (short)l;
    }
}
__device__ __forceinline__ uint2 pk4(USH a, USH b, USH c, USH d) {
    uint2 r;
    r.x = (unsigned)a | ((unsigned)b << 16);
    r.y = (unsigned)c | ((unsigned)d << 16);
    return r;
}

// ---------------------------------------------------------------------------
// Weight transpose+split: f32 [R][768] -> 3 bf16 planes [768][R].
// ---------------------------------------------------------------------------
struct TransArgs {
    const float* in[13];
    USH* o0[13]; USH* o1[13]; USH* o2[13];
    int R[13];
};

__global__ __launch_bounds__(256) void trans_k(TransArgs a) {
    const int mi = blockIdx.z;
    const float* __restrict__ in = a.in[mi];
    USH* __restrict__ o0 = a.o0[mi];
    USH* __restrict__ o1 = a.o1[mi];
    USH* __restrict__ o2 = a.o2[mi];
    const int R = a.R[mi];
    const int bx = blockIdx.x, by = blockIdx.y;
    if (bx * 32 >= R) return;
    __shared__ float t[32][33];
    const int tx = threadIdx.x & 31, ty = threadIdx.x >> 5;   // 32 x 8
#pragma unroll
    for (int i = 0; i < 4; ++i)
        t[ty + i * 8][tx] = in[(size_t)(bx * 32 + ty + i * 8) * 768 + by * 32 + tx];
    __syncthreads();
#pragma unroll
    for (int i = 0; i < 4; ++i) {
        USH h, m, l;
        split3(t[tx][ty + i * 8], h, m, l);
        const size_t o = (size_t)(by * 32 + ty + i * 8) * R + bx * 32 + tx;
        o0[o] = h; o1[o] = m; o2[o] = l;
    }
}

// ---------------------------------------------------------------------------
// Embedding gather: dst[m,:] = table[ids[m],:]  (f32 copy)
// grid: Mc*192/256, 4 floats / thread.
// ---------------------------------------------------------------------------
__global__ __launch_bounds__(256) void gather_k(const int* __restrict__ ids,
                                                const float* __restrict__ table,
                                                float* __restrict__ dst) {
    const int g  = blockIdx.x * 256 + threadIdx.x;
    const int m  = g / 192;
    const int c4 = (g - m * 192) * 4;
    const int id = ids[m];
    *(float4*)(dst + (size_t)m * DD + c4) =
        *(const float4*)(table + (size_t)id * DD + c4);
}

// ---------------------------------------------------------------------------
// GEMM: C[Mc,768] = A[Mc,K] @ W[K,768] + bias.   All f32 in/out.
// A f32 (A1 supplies k>=768 half for the K=1536 concat; else null).
// W pre-split 3 bf16 planes [768][K] (ldb).  6 MFMA passes.
// act: 0 none, 1 SiLU.  tout: store transposed C[col*Mc+row] (for V^T).
// Tile 128x128x32, 4 waves 2x2, each 4x4 MFMA tiles.
// ---------------------------------------------------------------------------
__global__ __launch_bounds__(256) void gemm_k(
    const float* __restrict__ A0, const float* __restrict__ A1,
    const USH* __restrict__ B0, const USH* __restrict__ B1, const USH* __restrict__ B2,
    int ldb, const float* __restrict__ bias,
    float* __restrict__ C, int K, int act, int tout, int Mc)
{
    __shared__ __align__(16) USH sA0[4096], sA1[4096], sA2[4096];
    __shared__ __align__(16) USH sB0[4096], sB1[4096], sB2[4096];

    const int tid  = threadIdx.x;
    const int lane = tid & 63;
    const int w    = tid >> 6;
    const int quad = lane >> 4, l15 = lane & 15;
    const int wm = (w >> 1) * 64, wn = (w & 1) * 64;
    const int gm0 = blockIdx.x * 128, gn0 = blockIdx.y * 128;

    const int i0 = tid * 2, i1 = tid * 2 + 1;
    const int r0 = i0 >> 2, c0 = (i0 & 3) << 3;
    const int r1 = i1 >> 2, c1 = (i1 & 3) << 3;

    const floatx4 zero = {0.f, 0.f, 0.f, 0.f};
    floatx4 acc[4][4];
#pragma unroll
    for (int i = 0; i < 4; ++i)
#pragma unroll
        for (int j = 0; j < 4; ++j) acc[i][j] = zero;

    for (int k0 = 0; k0 < K; k0 += 32) {
        const float* __restrict__ A = (k0 < 768) ? A0 : A1;
        const int kof = (k0 < 768) ? k0 : (k0 - 768);

        // ---- B staging: 3 pre-split planes, 2 uint4 per plane per thread ----
        *(uint4*)&sB0[r0 * 32 + c0] = *(const uint4*)(B0 + (size_t)(gn0 + r0) * ldb + k0 + c0);
        *(uint4*)&sB0[r1 * 32 + c1] = *(const uint4*)(B0 + (size_t)(gn0 + r1) * ldb + k0 + c1);
        *(uint4*)&sB1[r0 * 32 + c0] = *(const uint4*)(B1 + (size_t)(gn0 + r0) * ldb + k0 + c0);
        *(uint4*)&sB1[r1 * 32 + c1] = *(const uint4*)(B1 + (size_t)(gn0 + r1) * ldb + k0 + c1);
        *(uint4*)&sB2[r0 * 32 + c0] = *(const uint4*)(B2 + (size_t)(gn0 + r0) * ldb + k0 + c0);
        *(uint4*)&sB2[r1 * 32 + c1] = *(const uint4*)(B2 + (size_t)(gn0 + r1) * ldb + k0 + c1);

        // ---- A staging: f32 -> split3 -> 3 planes; 4 float4 per thread ----
#pragma unroll
        for (int u = 0; u < 4; ++u) {
            const int idx = tid + u * 256;           // [0,1024)
            const int r = idx >> 3, c = (idx & 7) * 4;
            const float4 v = *(const float4*)(A + (size_t)(gm0 + r) * 768 + kof + c);
            USH h[4], m[4], l[4];
            split3(v.x, h[0], m[0], l[0]);
            split3(v.y, h[1], m[1], l[1]);
            split3(v.z, h[2], m[2], l[2]);
            split3(v.w, h[3], m[3], l[3]);
            *(uint2*)&sA0[r * 32 + c] = pk4(h[0], h[1], h[2], h[3]);
            *(uint2*)&sA1[r * 32 + c] = pk4(m[0], m[1], m[2], m[3]);
            *(uint2*)&sA2[r * 32 + c] = pk4(l[0], l[1], l[2], l[3]);
        }
        __syncthreads();

        short8 a0[4], a1f[4], a2[4], b0[4], b1f[4], b2[4];
#pragma unroll
        for (int t = 0; t < 4; ++t) {
            const int ao = (wm + t * 16 + l15) * 32 + quad * 8;
            const int bo = (wn + t * 16 + l15) * 32 + quad * 8;
            a0[t]  = *(const short8*)&sA0[ao];
            a1f[t] = *(const short8*)&sA1[ao];
            a2[t]  = *(const short8*)&sA2[ao];
            b0[t]  = *(const short8*)&sB0[bo];
            b1f[t] = *(const short8*)&sB1[bo];
            b2[t]  = *(const short8*)&sB2[bo];
        }
        // 6 passes: hh, hm, mh, hl, lh, mm
#pragma unroll
        for (int i = 0; i < 4; ++i)
#pragma unroll
            for (int j = 0; j < 4; ++j) acc[i][j] = MFMA16(a0[i],  b0[j],  acc[i][j]);
#pragma unroll
        for (int i = 0; i < 4; ++i)
#pragma unroll
            for (int j = 0; j < 4; ++j) acc[i][j] = MFMA16(a0[i],  b1f[j], acc[i][j]);
#pragma unroll
        for (int i = 0; i < 4; ++i)
#pragma unroll
            for (int j = 0; j < 4; ++j) acc[i][j] = MFMA16(a1f[i], b0[j],  acc[i][j]);
#pragma unroll
        for (int i = 0; i < 4; ++i)
#pragma unroll
            for (int j = 0; j < 4; ++j) acc[i][j] = MFMA16(a0[i],  b2[j],  acc[i][j]);
#pragma unroll
        for (int i = 0; i < 4; ++i)
#pragma unroll
            for (int j = 0; j < 4; ++j) acc[i][j] = MFMA16(a2[i],  b0[j],  acc[i][j]);
#pragma unroll
        for (int i = 0; i < 4; ++i)
#pragma unroll
            for (int j = 0; j < 4; ++j) acc[i][j] = MFMA16(a1f[i], b1f[j], acc[i][j]);
        __syncthreads();
    }

    // ---- epilogue: bias (+SiLU, numpy op order) -> f32 store ----
#pragma unroll
    for (int j = 0; j < 4; ++j) {
        const int col = gn0 + wn + j * 16 + l15;
        const float bv = bias[col];
#pragma unroll
        for (int i = 0; i < 4; ++i) {
#pragma unroll
            for (int r = 0; r < 4; ++r) {
                const int row = gm0 + wm + i * 16 + quad * 4 + r;
                float x = acc[i][j][r] + bv;
                if (act == 1) {
                    const float s = 1.0f / (1.0f + expf(-x));   // sigmoid then mul
                    x = x * s;
                }
                const size_t o = tout ? ((size_t)col * Mc + row)
                                      : ((size_t)row * 768 + col);
                C[o] = x;
            }
        }
    }
}

// ---------------------------------------------------------------------------
// Interleaved RoPE over full 768 dim, in-place f32.  theta = f32-rounded
// double pow (matches numpy's correctly-rounded f32 powf); ang = s*theta f32.
// ---------------------------------------------------------------------------
__global__ __launch_bounds__(256) void rope_k(float* __restrict__ X) {
    const int p = blockIdx.x * 256 + threadIdx.x;
    const int m = p / 384;
    const int i = p - m * 384;
    const int s = m & (SS - 1);
    const float ef = (-2.0f * (float)i) / 768.0f;
    const float th = (float)pow(10000.0, (double)ef);
    const float ang = (float)s * th;
    float sn, cs;
    sincosf(ang, &sn, &cs);
    float2 x = *(float2*)(X + (size_t)m * DD + 2 * i);
    float2 y;
    y.x = x.x * cs - x.y * sn;
    y.y = x.y * cs + x.x * sn;
    *(float2*)(X + (size_t)m * DD + 2 * i) = y;
}

// ---------------------------------------------------------------------------
// Fused attention for one (local batch, head, 16-query tile).
// scores = (Q K^T) * 8 -> f32 softmax in LDS -> O = P V.
// Q,K f32 row-major [Mc,768]; V f32 transposed [768][Mc]; O f32 (may alias Q:
// block reads only its own Q rows/head-cols in phase 1, writes them phase 3).
// QK^T and PV both 6-pass with on-the-fly 3-plane splits; P split in LDS.
// grid: (SS/16, chB*H), block 256.
// ---------------------------------------------------------------------------
__global__ __launch_bounds__(256) void attn_k(
    const float* __restrict__ Q, const float* __restrict__ Kp,
    const float* __restrict__ Vt, float* __restrict__ O,
    int H, int hd, int Mc)
{
    __shared__ __align__(16) float S[16][520];      // scores; later P0|P1 overlay
    __shared__ __align__(16) USH P2buf[16 * 520];   // P lo plane
    __shared__ float red[16][16];
    __shared__ float stat[16];

    const int tid  = threadIdx.x;
    const int lane = tid & 63;
    const int w    = tid >> 6;
    const int quad = lane >> 4, l15 = lane & 15;
    const int b = blockIdx.y / H;
    const int h = blockIdx.y - b * H;
    const int q0 = blockIdx.x * 16;

    const floatx4 zero = {0.f, 0.f, 0.f, 0.f};

    // ---- phase 1: scores.  wave w covers keys [w*128, w*128+128) ----
    floatx4 acc[8];
#pragma unroll
    for (int t = 0; t < 8; ++t) acc[t] = zero;

    const size_t qbase = ((size_t)(b * SS + q0 + l15)) * DD + h * hd;
    const int nks = hd >> 5;
    for (int ks = 0; ks < nks; ++ks) {
        const int co = ks * 32 + quad * 8;
        float qv[8];
        *(float4*)&qv[0] = *(const float4*)(Q + qbase + co);
        *(float4*)&qv[4] = *(const float4*)(Q + qbase + co + 4);
        short8 qh, qm, ql;
        split3x8(qv, qh, qm, ql);
#pragma unroll
        for (int t = 0; t < 8; ++t) {
            const size_t kb = ((size_t)(b * SS + w * 128 + t * 16 + l15)) * DD + h * hd + co;
            float kv[8];
            *(float4*)&kv[0] = *(const float4*)(Kp + kb);
            *(float4*)&kv[4] = *(const float4*)(Kp + kb + 4);
            short8 kh, km, kl;
            split3x8(kv, kh, km, kl);
            acc[t] = MFMA16(qh, kh, acc[t]);
            acc[t] = MFMA16(qh, km, acc[t]);
            acc[t] = MFMA16(qm, kh, acc[t]);
            acc[t] = MFMA16(qh, kl, acc[t]);
            acc[t] = MFMA16(ql, kh, acc[t]);
            acc[t] = MFMA16(qm, km, acc[t]);
        }
    }
#pragma unroll
    for (int t = 0; t < 8; ++t)
#pragma unroll
        for (int r = 0; r < 4; ++r)
            S[quad * 4 + r][w * 128 + t * 16 + l15] = acc[t][r] * 8.0f;
    __syncthreads();

    // ---- phase 2: softmax (16 threads per row, 32 cols each) ----
    const int row = tid >> 4, c16 = tid & 15;
    const int cb = c16 * 32;
    float mx = -3.4e38f;
#pragma unroll 8
    for (int c = 0; c < 32; ++c) mx = fmaxf(mx, S[row][cb + c]);
    red[row][c16] = mx;
    __syncthreads();
    if (c16 == 0) {
        float m2 = red[row][0];
#pragma unroll
        for (int j = 1; j < 16; ++j) m2 = fmaxf(m2, red[row][j]);
        stat[row] = m2;
    }
    __syncthreads();
    mx = stat[row];
    float ev[32];
    float sum = 0.f;
#pragma unroll 8
    for (int c = 0; c < 32; ++c) {
        ev[c] = expf(S[row][cb + c] - mx);
        sum += ev[c];
    }
    red[row][c16] = sum;
    __syncthreads();
    if (c16 == 0) {
        float s2 = 0.f;
#pragma unroll
        for (int j = 0; j < 16; ++j) s2 += red[row][j];
        stat[row] = s2;
    }
    __syncthreads();                       // all S reads done -> overlay P
    const float den = stat[row];
    USH* const P0 = (USH*)&S[0][0];        // P hi plane  [0, 8320)
    USH* const P1 = P0 + 16 * 520;         // P mid plane [8320, 16640)
    USH* const P2 = P2buf;                 // P lo plane
#pragma unroll 8
    for (int c = 0; c < 32; ++c) {
        const float pr = ev[c] / den;      // divide, like numpy softmax
        USH hh, mm, ll;
        split3(pr, hh, mm, ll);
        P0[row * 520 + cb + c] = hh;
        P1[row * 520 + cb + c] = mm;
        P2[row * 520 + cb + c] = ll;
    }
    __syncthreads();

    // ---- phase 3: O = P V.  wave w covers n-tiles nt = w, w+4, ... ----
    const int nnt = hd >> 4;
    for (int nt = w; nt < nnt; nt += 4) {
        floatx4 o = zero;
        const int colg = h * hd + nt * 16 + l15;
        const size_t vb = (size_t)colg * Mc + b * SS;
        for (int ks = 0; ks < 16; ++ks) {
            const int ko = ks * 32 + quad * 8;
            const short8 ph = *(const short8*)&P0[l15 * 520 + ko];
            const short8 pm = *(const short8*)&P1[l15 * 520 + ko];
            const short8 pl = *(const short8*)&P2[l15 * 520 + ko];
            float vv[8];
            *(float4*)&vv[0] = *(const float4*)(Vt + vb + ko);
            *(float4*)&vv[4] = *(const float4*)(Vt + vb + ko + 4);
            short8 vh, vm, vl;
            split3x8(vv, vh, vm, vl);
            o = MFMA16(ph, vh, o);
            o = MFMA16(ph, vm, o);
            o = MFMA16(pm, vh, o);
            o = MFMA16(ph, vl, o);
            o = MFMA16(pl, vh, o);
            o = MFMA16(pm, vm, o);
        }
#pragma unroll
        for (int r = 0; r < 4; ++r) {
            const int orow = b * SS + q0 + quad * 4 + r;
            O[(size_t)orow * 768 + colg] = o[r];
        }
    }
}

// ---------------------------------------------------------------------------
// Gate: x = x * softmax(x, row) + x, in-place f32. 1 block / row.
// ---------------------------------------------------------------------------
__global__ __launch_bounds__(256) void gate_k(float* __restrict__ X) {
    __shared__ float red[256];
    const int r = blockIdx.x, tid = threadIdx.x;
    const size_t base = (size_t)r * DD;
    float x[3];
#pragma unroll
    for (int j = 0; j < 3; ++j) x[j] = X[base + tid + j * 256];
    float mx = fmaxf(x[0], fmaxf(x[1], x[2]));
    red[tid] = mx;
    __syncthreads();
    for (int s = 128; s > 0; s >>= 1) {
        if (tid < s) red[tid] = fmaxf(red[tid], red[tid + s]);
        __syncthreads();
    }
    mx = red[0];
    __syncthreads();
    float e[3];
    float sum = 0.f;
#pragma unroll
    for (int j = 0; j < 3; ++j) { e[j] = expf(x[j] - mx); sum += e[j]; }
    red[tid] = sum;
    __syncthreads();
    for (int s = 128; s > 0; s >>= 1) {
        if (tid < s) red[tid] += red[tid + s];
        __syncthreads();
    }
    const float den = red[0];
#pragma unroll
    for (int j = 0; j < 3; ++j)
        X[base + tid + j * 256] = x[j] * (e[j] / den) + x[j];
}

// ---------------------------------------------------------------------------
// Final: es = text + F1 + F2 + F3 ;  out = es * softmax(es,row) + es  (f32)
// ---------------------------------------------------------------------------
__global__ __launch_bounds__(256) void final_k(
    const float* __restrict__ text,
    const float* __restrict__ F1, const float* __restrict__ F2,
    const float* __restrict__ F3, float* __restrict__ out)
{
    __shared__ float red[256];
    const int r = blockIdx.x, tid = threadIdx.x;
    const size_t base = (size_t)r * DD;
    float x[3];
#pragma unroll
    for (int j = 0; j < 3; ++j) {
        const int c = tid + j * 256;
        x[j] = ((text[base + c] + F1[base + c]) + F2[base + c]) + F3[base + c];
    }
    float mx = fmaxf(x[0], fmaxf(x[1], x[2]));
    red[tid] = mx;
    __syncthreads();
    for (int s = 128; s > 0; s >>= 1) {
        if (tid < s) red[tid] = fmaxf(red[tid], red[tid + s]);
        __syncthreads();
    }
    mx = red[0];
    __syncthreads();
    float e[3];
    float sum = 0.f;
#pragma unroll
    for (int j = 0; j < 3; ++j) { e[j] = expf(x[j] - mx); sum += e[j]; }
    red[tid] = sum;
    __syncthreads();
    for (int s = 128; s > 0; s >>= 1) {
        if (tid < s) red[tid] += red[tid + s];
        __syncthreads();
    }
    const float den = red[0];
#pragma unroll
    for (int j = 0; j < 3; ++j) {
        const int c = tid + j * 256;
        out[base + c] = x[j] * (e[j] / den) + x[j];
    }
}

// ===========================================================================
// Host orchestration — batch-chunked, 6 f32 planes.
// ===========================================================================
extern "C" void kernel_launch(void* const* d_in, const int* in_sizes, int n_in,
                              void* d_out, int out_size, void* d_ws, size_t ws_size,
                              hipStream_t stream)
{
    (void)in_sizes; (void)n_in; (void)out_size;

    const float* text    = (const float*)d_in[0];
    const int*   vis_ids = (const int*)d_in[1];
    const int*   ac_ids  = (const int*)d_in[2];
    const float* vis_tab = (const float*)d_in[3];
    const float* ac_tab  = (const float*)d_in[4];
    const float* hv_wq = (const float*)d_in[5],  *hv_bq = (const float*)d_in[6];
    const float* hv_wk = (const float*)d_in[7],  *hv_bk = (const float*)d_in[8];
    const float* hv_wv = (const float*)d_in[9],  *hv_bv = (const float*)d_in[10];
    const float* ha_wq = (const float*)d_in[11], *ha_bq = (const float*)d_in[12];
    const float* ha_wk = (const float*)d_in[13], *ha_bk = (const float*)d_in[14];
    const float* ha_wv = (const float*)d_in[15], *ha_bv = (const float*)d_in[16];
    const float* ht_wq = (const float*)d_in[17], *ht_bq = (const float*)d_in[18];
    const float* ht_wk = (const float*)d_in[19], *ht_bk = (const float*)d_in[20];
    const float* ht_wv = (const float*)d_in[21], *ht_bv = (const float*)d_in[22];
    const float* ht_fcw = (const float*)d_in[23], *ht_fcb = (const float*)d_in[24];
    const float* ffn_w1 = (const float*)d_in[25], *ffn_b1 = (const float*)d_in[26];
    const float* ffn_w2 = (const float*)d_in[27], *ffn_b2 = (const float*)d_in[28];
    const float* cat_w  = (const float*)d_in[29], *cat_b  = (const float*)d_in[30];

    // ---------------- workspace sizing ----------------
    const size_t SQ   = (size_t)768 * 768;                     // USH per plane
    const size_t WUSH = 3 * (12 * SQ + (size_t)768 * 1536);    // 24,772,608 USH
    int Mc = 0;
    for (int cand = MM; cand >= 512; cand >>= 1) {
        const size_t need = WUSH * sizeof(USH) + (size_t)6 * cand * 768 * sizeof(float);
        if (need <= ws_size) { Mc = cand; break; }
    }
    if (Mc == 0) return;    // diagnostic: wrong output, not a fault
    const int nchunk = MM / Mc;
    const int chB    = Mc / SS;

    USH* p = (USH*)d_ws;
    USH *wt0[13], *wt1[13], *wt2[13];
    for (int i = 0; i < 13; ++i) {
        const size_t sz = (i == 12) ? (size_t)768 * 1536 : SQ;
        wt0[i] = p; p += sz;
        wt1[i] = p; p += sz;
        wt2[i] = p; p += sz;
    }
    const size_t PSZ = (size_t)Mc * 768;       // floats per plane
    float* fp = (float*)p;
    float *A_ = fp + 0 * PSZ, *B_ = fp + 1 * PSZ, *C_ = fp + 2 * PSZ;
    float *D_ = fp + 3 * PSZ, *E_ = fp + 4 * PSZ, *F_ = fp + 5 * PSZ;

    // weight indices: 0 hv_wq 1 hv_wk 2 hv_wv 3 ha_wq 4 ha_wk 5 ha_wv
    //                 6 ht_wq 7 ht_wk 8 ht_wv 9 ht_fcw 10 ffn_w1 11 ffn_w2 12 cat_w
    TransArgs ta;
    const float* tin[13] = {hv_wq, hv_wk, hv_wv, ha_wq, ha_wk, ha_wv,
                            ht_wq, ht_wk, ht_wv, ht_fcw, ffn_w1, ffn_w2, cat_w};
    for (int i = 0; i < 13; ++i) {
        ta.in[i] = tin[i]; ta.o0[i] = wt0[i]; ta.o1[i] = wt1[i]; ta.o2[i] = wt2[i];
        ta.R[i] = (i == 12) ? 1536 : 768;
    }
    trans_k<<<dim3(48, 24, 13), 256, 0, stream>>>(ta);

    const dim3 gg(Mc / 128, DD / 128), gb(256);
    const int ropeg = Mc * 384 / 256;
    const float* NULF = nullptr;

#define GEMM(A0P, A1P, WI, LDB, BIAS, CP, KK, ACT, TOUT) \
    gemm_k<<<gg, gb, 0, stream>>>(A0P, A1P, wt0[WI], wt1[WI], wt2[WI], LDB, BIAS, CP, KK, ACT, TOUT, Mc)
#define ROPE(XP) rope_k<<<ropeg, 256, 0, stream>>>(XP)
#define ATTN(QP, KP, VP, OP, HH, HD) \
    attn_k<<<dim3(SS / 16, chB * (HH)), 256, 0, stream>>>(QP, KP, VP, OP, HH, HD, Mc)
#define GATE(XP) gate_k<<<Mc, 256, 0, stream>>>(XP)

    for (int c = 0; c < nchunk; ++c) {
        const float* tx = text + (size_t)c * PSZ;
        const int* vi = vis_ids + (size_t)c * Mc;
        const int* ai = ac_ids  + (size_t)c * Mc;
        float* outc = (float*)d_out + (size_t)c * PSZ;

        // ---- embeddings: Ev -> A, Ea -> B ----
        gather_k<<<Mc * 192 / 256, 256, 0, stream>>>(vi, vis_tab, A_);
        gather_k<<<Mc * 192 / 256, 256, 0, stream>>>(ai, ac_tab, B_);

        // ---- stage A: v1 = hv(text, Ev) -> F ----
        GEMM(tx, NULF, 0, 768, hv_bq, C_, 768, 0, 0);    // Q
        GEMM(A_, NULF, 1, 768, hv_bk, D_, 768, 0, 0);    // K <- Ev
        GEMM(A_, NULF, 2, 768, hv_bv, E_, 768, 0, 1);    // V^T <- Ev
        ROPE(C_); ROPE(D_);
        ATTN(C_, D_, E_, F_, 1, 768);                    // v1 -> F

        // ---- a1 = ha(text, Ea) -> A (Ev dead) ----
        GEMM(tx, NULF, 3, 768, ha_bq, C_, 768, 0, 0);
        GEMM(B_, NULF, 4, 768, ha_bk, D_, 768, 0, 0);
        GEMM(B_, NULF, 5, 768, ha_bv, E_, 768, 0, 1);
        ROPE(C_); ROPE(D_);
        ATTN(C_, D_, E_, A_, 1, 768);                    // a1 -> A

        // ---- stage C: v2 = hv(v1, a1) -> C (aliases its Q) ----
        GEMM(F_, NULF, 0, 768, hv_bq, C_, 768, 0, 0);
        GEMM(A_, NULF, 1, 768, hv_bk, D_, 768, 0, 0);
        GEMM(A_, NULF, 2, 768, hv_bv, E_, 768, 0, 1);
        ROPE(C_); ROPE(D_);
        ATTN(C_, D_, E_, C_, 1, 768);                    // v2 -> C

        // ---- a2 = ha(a1, v1) -> B (aliases its Q) ----
        GEMM(A_, NULF, 3, 768, ha_bq, B_, 768, 0, 0);
        GEMM(F_, NULF, 4, 768, ha_bk, D_, 768, 0, 0);
        GEMM(F_, NULF, 5, 768, ha_bv, E_, 768, 0, 1);
        ROPE(B_); ROPE(D_);
        ATTN(B_, D_, E_, B_, 1, 768);                    // a2 -> B

        // ---- F1 = ffn(gate(cat(v1,a1) @ cat_w)) -> F ----
        GEMM(F_, A_, 12, 1536, cat_b, D_, 1536, 0, 0);   // T1
        GATE(D_);
        GEMM(D_, NULF, 10, 768, ffn_b1, E_, 768, 1, 0);  // H (SiLU)
        GEMM(E_, NULF, 11, 768, ffn_b2, F_, 768, 0, 0);  // F1 (v1 dead)

        // ---- F2 = ffn(gate(cat(v2,a2) @ cat_w)) -> B ----
        GEMM(C_, B_, 12, 1536, cat_b, A_, 1536, 0, 0);   // T2 (a1 dead)
        GATE(A_);
        GEMM(A_, NULF, 10, 768, ffn_b1, C_, 768, 1, 0);  // H (v2 dead)
        GEMM(C_, NULF, 11, 768, ffn_b2, B_, 768, 0, 0);  // F2 (a2 dead)

        // ---- stage D: F3 = ffn(gate(fc(ht(F1, text)))) -> D ----
        GEMM(F_, NULF, 6, 768, ht_bq, C_, 768, 0, 0);    // Q <- F1
        GEMM(tx, NULF, 7, 768, ht_bk, D_, 768, 0, 0);    // K
        GEMM(tx, NULF, 8, 768, ht_bv, E_, 768, 0, 1);    // V^T
        ROPE(C_); ROPE(D_);
        ATTN(C_, D_, E_, C_, 8, 96);                     // AO aliases Q
        GEMM(C_, NULF, 9, 768, ht_fcb, A_, 768, 0, 0);   // fc
        GATE(A_);
        GEMM(A_, NULF, 10, 768, ffn_b1, C_, 768, 1, 0);  // H
        GEMM(C_, NULF, 11, 768, ffn_b2, D_, 768, 0, 0);  // F3

        // ---- final: gate(text + F1 + F2 + F3) -> out (f32) ----
        final_k<<<Mc, 256, 0, stream>>>(tx, F_, B_, D_, outc);
    }

#undef GEMM
#undef ROPE
#undef ATTN
#undef GATE
}